// Round 2
// baseline (235.413 us; speedup 1.0000x reference)
//
#include <hip/hip_runtime.h>
#include <stdint.h>

// out[p,b,o] = sum_i x*w0 + (1-x)*w1,  x,w in {0,1}
//            = sum_iw popc( (x & w0) | (~x & w1) )   -- one v_bfi_b32 + one
//              accumulating v_bcnt per word. Exact.
//
// R10: R8 structure (x in LDS via lgkmcnt domain, w-exclusive vmcnt FIFO,
// fully-unrolled stages) but TWO o-columns per thread (lane, lane+64).
// Rationale: R8's LDS broadcast reads (128 ds_read_b128 / wave / stage
// ~= 87us of LDS pipe per CU) were co-dominant with the ~90us/CU HBM
// w-stream. The LDS:compute ratio is set by columns-per-thread; doubling
// columns halves LDS traffic per unit work with no extra VALU per unit
// work (R9's readlane attempt ADDED 25% VALU and regressed).
//   Block 1024 thr = whole p x 128 cols, grid 256 -> 1 block/CU, 16 waves.
//   LDS 64 KB: xs[512][16] (32 KB, current stage x) +
//              wbuf[2][16][128][2] (32 KB, double-buffered packed w).
//   Per stage: 16 w bursts (8-row dword strips, 2 cols x 2 mats x 4 octs),
//   two rotating 8-reg slots, 2 extract+issue pairs per HALF; x refill
//   issued at stage start, written back at stage end (vmcnt drained there
//   anyway). acc u16-packed pairs (out <= 2048, exact), 2 acc arrays.

#define NP 16
#define NB 512
#define NI 2048
#define NO 2048
#define JW 64               // u32 words per i-row
#define OG 128              // o-columns per block (2 per lane)
#define NOG (NO / OG)       // 16
#define STW 16              // i-words per stage
#define NSTAGE (JW / STW)   // 4

__global__ __launch_bounds__(256) void pack_x_kernel(const float* __restrict__ x,
                                                     uint32_t* __restrict__ xp) {
    const int gtid = blockIdx.x * 256 + threadIdx.x;
    const int row  = gtid >> 6;     // p*NB + b
    const int lane = gtid & 63;
    const float* src = x + (size_t)row * NI;
    unsigned long long* dst = (unsigned long long*)(xp + (size_t)row * JW);
#pragma unroll 4
    for (int k = 0; k < NI / 64; ++k) {
        const float v = src[k * 64 + lane];
        const unsigned long long m = __ballot(v != 0.0f);
        if (lane == 0) dst[k] = m;
    }
}

// issue 8-row w burst b of i-word gi:
//   b&8 : column lane+64 (else lane)    b&4 : mat1 (else mat0)    b&3 : row-oct
#define WISSUE(dst, gi, b) do {                                                \
    const float* _s = wcol0 + (((b) & 4) ? (size_t)NP * wq : (size_t)0)        \
                    + (((b) & 8) ? 64 : 0)                                     \
                    + (size_t)((gi) * 32 + ((b) & 3) * 8) * NO;                \
    _Pragma("unroll")                                                          \
    for (int _u = 0; _u < 8; ++_u) dst[_u] = __float_as_uint(_s[(size_t)_u * NO]); \
} while (0)

// fold burst b's 8 loaded floats into bits (b&3)*8.. of nwd[b>>2]
#define WEXTRACT(src, b) do {                                                  \
    uint32_t _pt = 0;                                                          \
    _Pragma("unroll")                                                          \
    for (int _u = 0; _u < 8; ++_u) _pt |= ((src[_u] >> 23) & 1u) << _u;        \
    nwd[(b) >> 2] |= _pt << (((b) & 3) * 8);                                   \
} while (0)

// issue this thread's 8 x-words (stage s_) into xv[8]; write to xs later
#define XISSUE(s_) do {                                                        \
    const uint32_t* _xsrc = xp + ((size_t)p * NB + (tid >> 1)) * JW            \
                          + (s_) * STW + (tid & 1) * 8;                        \
    *(uint4*)&xv[0] = *(const uint4*)_xsrc;                                    \
    *(uint4*)&xv[4] = *(const uint4*)(_xsrc + 4);                              \
} while (0)

#define XWRITE() do {                                                          \
    *(uint4*)&xs[tid >> 1][(tid & 1) * 8]     = *(uint4*)&xv[0];               \
    *(uint4*)&xs[tid >> 1][(tid & 1) * 8 + 4] = *(uint4*)&xv[4];               \
} while (0)

// load the 4-iword w window for window `win` from wbuf[cur_], both columns
#define WWIN(cur_, win) do {                                                   \
    _Pragma("unroll")                                                          \
    for (int _j = 0; _j < 4; ++_j) {                                           \
        const uint2 _pa = *(const uint2*)&wbuf[cur_][(win) * 4 + _j][lane][0]; \
        w0a[_j] = _pa.x; w1a[_j] = _pa.y;                                      \
        const uint2 _pb = *(const uint2*)&wbuf[cur_][(win) * 4 + _j][lane + 64][0]; \
        w0b[_j] = _pb.x; w1b[_j] = _pb.y;                                      \
    }                                                                          \
} while (0)

// compute 8 row-pairs (half h) of window win for BOTH columns;
// x via LDS broadcast reads (one pair of b128 feeds 2 columns of compute)
#define HALF(win, h) do {                                                      \
    _Pragma("unroll")                                                          \
    for (int _t = 0; _t < 8; ++_t) {                                           \
        const int _pr = (h) * 8 + _t;                                          \
        const uint4 _xa = *(const uint4*)&xs[wv * 32 + 2 * _pr][(win) * 4];    \
        const uint4 _xb = *(const uint4*)&xs[wv * 32 + 2 * _pr + 1][(win) * 4];\
        uint32_t _tA0 = __popc((_xa.x & w0a[0]) | (~_xa.x & w1a[0]))           \
                      + __popc((_xa.y & w0a[1]) | (~_xa.y & w1a[1]))           \
                      + __popc((_xa.z & w0a[2]) | (~_xa.z & w1a[2]))           \
                      + __popc((_xa.w & w0a[3]) | (~_xa.w & w1a[3]));          \
        uint32_t _tB0 = __popc((_xb.x & w0a[0]) | (~_xb.x & w1a[0]))           \
                      + __popc((_xb.y & w0a[1]) | (~_xb.y & w1a[1]))           \
                      + __popc((_xb.z & w0a[2]) | (~_xb.z & w1a[2]))           \
                      + __popc((_xb.w & w0a[3]) | (~_xb.w & w1a[3]));          \
        uint32_t _tA1 = __popc((_xa.x & w0b[0]) | (~_xa.x & w1b[0]))           \
                      + __popc((_xa.y & w0b[1]) | (~_xa.y & w1b[1]))           \
                      + __popc((_xa.z & w0b[2]) | (~_xa.z & w1b[2]))           \
                      + __popc((_xa.w & w0b[3]) | (~_xa.w & w1b[3]));          \
        uint32_t _tB1 = __popc((_xb.x & w0b[0]) | (~_xb.x & w1b[0]))           \
                      + __popc((_xb.y & w0b[1]) | (~_xb.y & w1b[1]))           \
                      + __popc((_xb.z & w0b[2]) | (~_xb.z & w1b[2]))           \
                      + __popc((_xb.w & w0b[3]) | (~_xb.w & w1b[3]));          \
        acc0[_pr] += _tA0 + (_tB0 << 16);                                      \
        acc1[_pr] += _tA1 + (_tB1 << 16);                                      \
    }                                                                          \
} while (0)

// one pipeline stage: compute stage s_ from wbuf[cur_]/xs while prefetching
// stage s_+1 (16 w bursts, 2 rotating slots, 2 extract+issue pairs per HALF).
#define STAGE(s_, cur_, more_) do {                                            \
    const int _gi1 = ((s_) + 1) * STW + wv;                                    \
    if (more_) { XISSUE((s_) + 1);                                             \
                 nwd[0] = 0; nwd[1] = 0; nwd[2] = 0; nwd[3] = 0;               \
                 WISSUE(va, _gi1, 0); WISSUE(vb, _gi1, 1); }                   \
    WWIN(cur_, 0); HALF(0, 0);                                                 \
    if (more_) { WEXTRACT(va, 0); WISSUE(va, _gi1, 2);                         \
                 WEXTRACT(vb, 1); WISSUE(vb, _gi1, 3); }                       \
    HALF(0, 1);                                                                \
    if (more_) { WEXTRACT(va, 2); WISSUE(va, _gi1, 4);                         \
                 WEXTRACT(vb, 3); WISSUE(vb, _gi1, 5);                         \
                 wbuf[(cur_) ^ 1][wv][lane][0] = nwd[0]; }                     \
    WWIN(cur_, 1); HALF(1, 0);                                                 \
    if (more_) { WEXTRACT(va, 4); WISSUE(va, _gi1, 6);                         \
                 WEXTRACT(vb, 5); WISSUE(vb, _gi1, 7); }                       \
    HALF(1, 1);                                                                \
    if (more_) { WEXTRACT(va, 6); WISSUE(va, _gi1, 8);                         \
                 WEXTRACT(vb, 7); WISSUE(vb, _gi1, 9);                         \
                 wbuf[(cur_) ^ 1][wv][lane][1] = nwd[1]; }                     \
    WWIN(cur_, 2); HALF(2, 0);                                                 \
    if (more_) { WEXTRACT(va, 8); WISSUE(va, _gi1, 10);                        \
                 WEXTRACT(vb, 9); WISSUE(vb, _gi1, 11); }                      \
    HALF(2, 1);                                                                \
    if (more_) { WEXTRACT(va, 10); WISSUE(va, _gi1, 12);                       \
                 WEXTRACT(vb, 11); WISSUE(vb, _gi1, 13);                       \
                 wbuf[(cur_) ^ 1][wv][lane + 64][0] = nwd[2]; }                \
    WWIN(cur_, 3); HALF(3, 0);                                                 \
    if (more_) { WEXTRACT(va, 12); WISSUE(va, _gi1, 14);                       \
                 WEXTRACT(vb, 13); WISSUE(vb, _gi1, 15); }                     \
    HALF(3, 1);                                                                \
    if (more_) { WEXTRACT(va, 14); WEXTRACT(vb, 15);                           \
                 wbuf[(cur_) ^ 1][wv][lane + 64][1] = nwd[3];                  \
                 __syncthreads(); XWRITE(); __syncthreads(); }                 \
} while (0)

__global__ __launch_bounds__(1024) void evo_main(const float* __restrict__ w,
                                                 const uint32_t* __restrict__ xp,
                                                 float* __restrict__ out) {
    __shared__ uint32_t wbuf[2][STW][OG][2];   // 32 KB, double-buffered w bits
    __shared__ uint32_t xs[NB][STW];           // 32 KB, current stage's x bits

    const int tid  = threadIdx.x;
    const int lane = tid & 63;
    const int wv   = __builtin_amdgcn_readfirstlane(tid >> 6);  // 0..15
    const int p    = blockIdx.x >> 4;   // 0..15
    const int og   = blockIdx.x & 15;   // 0..15

    const size_t wq = (size_t)NI * NO;
    const float* wcol0 = w + (size_t)p * wq + (size_t)(og * OG + lane);

    uint32_t acc0[16], acc1[16];  // low16 = row 2t, high16 = row 2t+1 (<=2048)
#pragma unroll
    for (int t = 0; t < 16; ++t) { acc0[t] = 0; acc1[t] = 0; }

    uint32_t xv[8], va[8], vb[8];
    uint32_t w0a[4], w1a[4], w0b[4], w1b[4];
    uint32_t nwd[4];

    // ---- prologue: stage-0 x words + w i-word wv, 2-slot burst rotation ----
    XISSUE(0);
    {
        const int gi = wv;
        nwd[0] = 0; nwd[1] = 0; nwd[2] = 0; nwd[3] = 0;
        WISSUE(va, gi, 0);  WISSUE(vb, gi, 1);
        WEXTRACT(va, 0);    WISSUE(va, gi, 2);
        WEXTRACT(vb, 1);    WISSUE(vb, gi, 3);
        WEXTRACT(va, 2);    WISSUE(va, gi, 4);
        WEXTRACT(vb, 3);    WISSUE(vb, gi, 5);
        wbuf[0][wv][lane][0] = nwd[0];
        WEXTRACT(va, 4);    WISSUE(va, gi, 6);
        WEXTRACT(vb, 5);    WISSUE(vb, gi, 7);
        WEXTRACT(va, 6);    WISSUE(va, gi, 8);
        WEXTRACT(vb, 7);    WISSUE(vb, gi, 9);
        wbuf[0][wv][lane][1] = nwd[1];
        WEXTRACT(va, 8);    WISSUE(va, gi, 10);
        WEXTRACT(vb, 9);    WISSUE(vb, gi, 11);
        WEXTRACT(va, 10);   WISSUE(va, gi, 12);
        WEXTRACT(vb, 11);   WISSUE(vb, gi, 13);
        wbuf[0][wv][lane + 64][0] = nwd[2];
        WEXTRACT(va, 12);   WISSUE(va, gi, 14);
        WEXTRACT(vb, 13);   WISSUE(vb, gi, 15);
        WEXTRACT(va, 14);
        WEXTRACT(vb, 15);
        wbuf[0][wv][lane + 64][1] = nwd[3];
    }
    XWRITE();
    __syncthreads();

    // ---- 4 stages, fully unrolled; last one compute-only ----
    STAGE(0, 0, true);
    STAGE(1, 1, true);
    STAGE(2, 0, true);
    STAGE(3, 1, false);

    // ---- epilogue: unpack u16 pairs, coalesced stores (2 columns) ----
    float* obase = out + ((size_t)p * NB + wv * 32) * NO + (size_t)og * OG + lane;
#pragma unroll
    for (int t = 0; t < 16; ++t) {
        obase[(size_t)(2 * t) * NO]          = (float)(acc0[t] & 0xFFFFu);
        obase[(size_t)(2 * t) * NO + 64]     = (float)(acc1[t] & 0xFFFFu);
        obase[(size_t)(2 * t + 1) * NO]      = (float)(acc0[t] >> 16);
        obase[(size_t)(2 * t + 1) * NO + 64] = (float)(acc1[t] >> 16);
    }
}

extern "C" void kernel_launch(void* const* d_in, const int* in_sizes, int n_in,
                              void* d_out, int out_size, void* d_ws, size_t ws_size,
                              hipStream_t stream) {
    const float* x = (const float*)d_in[0];   // (16,512,2048) fp32 {0,1}
    const float* w = (const float*)d_in[1];   // (2,16,1,2048,2048) fp32 {0,1}
    float* out     = (float*)d_out;           // (16,512,2048) fp32
    uint32_t* xp   = (uint32_t*)d_ws;         // 2 MB packed x

    pack_x_kernel<<<dim3((NP * NB * 64) / 256), dim3(256), 0, stream>>>(x, xp);
    evo_main<<<dim3(NP * NOG), dim3(1024), 0, stream>>>(w, xp, out);
}